// Round 9
// baseline (214.402 us; speedup 1.0000x reference)
//
#include <hip/hip_runtime.h>

#define CCH 256
#define HH  256
#define WW  256
#define HWSZ (HH * WW)
#define NROI 512
#define RBIN 7
#define NBIN (RBIN * RBIN)            // 49
#define NPTS (NROI * 196)             // 100352 sample points
#define NTILE 64                      // 8x8 tiles of 32x32 px
#define CAP NPTS                      // worst-case points per tile

// ws layout (in 32-bit words):
//   [0, 25088)                pooled keys (u32, order-preserving float map)
//   [25088, 25152)            gcount[64] tile counters
//   [32768, 32768 + 64*CAP)   per-tile point lists
#define POOLED_OFF 0
#define GCOUNT_OFF 25088
#define LISTS_OFF  32768
#define WS_WORDS_NEEDED ((size_t)LISTS_OFF + (size_t)NTILE * CAP)

typedef float vfloat4 __attribute__((ext_vector_type(4)));

// Shared coordinate computation (must be the same expression tree in bin and
// scatter; +-1 ULP divergence between call sites only perturbs weights by
// epsilon -- LDS indexing always comes from the STORED entry, never recompute).
__device__ __forceinline__ void point_xy(const float4 r, int p,
                                         float& y, float& x, int& bin) {
    const int py = p / 14, px = p % 14;
    const int by = py >> 1, sy = py & 1;
    const int bx = px >> 1, sx = px & 1;
    const float sh = (r.z - r.x) / (float)RBIN;   // rois: [y0, x0, y1, x1]
    const float sw = (r.w - r.y) / (float)RBIN;
    y = r.x + sh * (float)by + ((sy == 0) ? (sh / 3.0f) : (2.0f * sh / 3.0f));
    x = r.y + sw * (float)bx + ((sx == 0) ? (sw / 3.0f) : (2.0f * sw / 3.0f));
    bin = by * RBIN + bx;
}

// ---------------- Kernel 0: zero pooled keys + tile counters ----------------
__global__ __launch_bounds__(256)
void init_ws(unsigned* __restrict__ ws) {
    const int i = blockIdx.x * 256 + threadIdx.x;
    if (i < GCOUNT_OFF + NTILE) ws[i] = 0;        // pooled + gcount contiguous
}

// ---------------- Kernel 1: bin sample points into 32x32 tiles --------------
// 128 blocks x 1024 threads; block = 4 rois (784 points). LDS-aggregated
// append: per-tile LDS counts -> one global atomicAdd per (block, tile).
__global__ __launch_bounds__(1024)
void bin_points(const float* __restrict__ rois, unsigned* __restrict__ ws) {
    __shared__ unsigned cnt[NTILE];
    __shared__ unsigned base[NTILE];
    const int t = threadIdx.x;
    if (t < NTILE) cnt[t] = 0;
    __syncthreads();

    unsigned entry = 0, rank = 0;
    int tile = 0;
    const bool active = (t < 784);
    if (active) {
        const int n = blockIdx.x * 4 + t / 196;
        const int p = t % 196;
        const float4 r = ((const float4*)rois)[n];
        float y, x; int bin;
        point_xy(r, p, y, x, bin);
        const int iy1 = min(max((int)floorf(y), 0), HH - 1);
        const int ix1 = min(max((int)floorf(x), 0), WW - 1);
        tile = (iy1 >> 5) * 8 + (ix1 >> 5);
        entry = (unsigned)n | ((unsigned)p << 9) |
                ((unsigned)(iy1 & 31) << 17) | ((unsigned)(ix1 & 31) << 22);
        rank = atomicAdd(&cnt[tile], 1u);
    }
    __syncthreads();
    if (t < NTILE) base[t] = atomicAdd(&ws[GCOUNT_OFF + t], cnt[t]);
    __syncthreads();
    if (active)
        ws[LISTS_OFF + (size_t)tile * CAP + base[tile] + rank] = entry;
}

// ---------------- Kernel 2: scatter-pool over one feature pass --------------
// grid (16 ch-chunks, 64 tiles), block 256 = 4 waves. Stage 33x33x16 fp32
// (69.7 KB LDS, 2 blocks/CU). Quad of lanes per point: 4x ds_read_b128
// (16B-aligned: (ly*33+lx)*64B + q*16B), bilinear w/ reference clip
// semantics, quad shuffle-max, atomicMax (order-preserving u32 map).
__global__ __launch_bounds__(256)
void scatter_pool(const float* __restrict__ feat,
                  const float* __restrict__ rois,
                  unsigned* __restrict__ ws) {
    __shared__ __align__(16) float sf[33 * 33 * 16];
    const int t    = threadIdx.x;
    const int tile = blockIdx.y;
    const int c0   = blockIdx.x * 16;
    const int ty0  = (tile >> 3) * 32;
    const int tx0  = (tile & 7) * 32;

    const unsigned npts = ws[GCOUNT_OFF + tile];
    if (npts == 0) return;                        // uniform: skip empty tiles

    // stage tile + 1px halo; edge rows/cols clamp (matches corner clipping)
    for (int i = t; i < 33 * 33 * 16; i += 256) {
        const int ch  = i / 1089;                 // 1089 = 33*33
        const int rem = i - ch * 1089;
        const int yy  = rem / 33;
        const int xx  = rem - yy * 33;
        const int gy  = min(ty0 + yy, HH - 1);
        const int gx  = min(tx0 + xx, WW - 1);
        sf[(yy * 33 + xx) * 16 + ch] =
            feat[(size_t)(c0 + ch) * HWSZ + gy * WW + gx];
    }
    __syncthreads();

    const unsigned* list = ws + LISTS_OFF + (size_t)tile * CAP;
    unsigned* pooled = ws + POOLED_OFF;
    const int q   = t & 3;                        // 4-ch sub-chunk within 16
    const int wid = t >> 6;                       // wave 0..3
    const int lq  = (t & 63) >> 2;                // point slot 0..15

    for (unsigned j0 = (unsigned)wid * 16; j0 < npts; j0 += 64) {
        const unsigned j = j0 + lq;
        const bool valid = (j < npts);            // uniform per quad
        float m = -INFINITY;
        int n = 0, bin = 0;
        if (valid) {
            const unsigned e = list[j];
            n = e & 511;
            const int p  = (e >> 9) & 255;
            const int ly = (e >> 17) & 31;
            const int lx = (e >> 22) & 31;
            const float4 r = ((const float4*)rois)[n];
            float y, x;
            point_xy(r, p, y, x, bin);
            const int iy1 = ty0 + ly, ix1 = tx0 + lx;
            const int iy2 = min(iy1 + 1, HH - 1);
            const int ix2 = min(ix1 + 1, WW - 1);
            // weights from clipped indices (zero-strip at 255 preserved);
            // LDS rows ly+1 / lx+1 hold the clamped duplicates, so content
            // always equals the clipped corner.
            const float wy1 = y - (float)iy1, wy2 = (float)iy2 - y;
            const float wx1 = x - (float)ix1, wx2 = (float)ix2 - x;
            const int b = (ly * 33 + lx) * 16 + q * 4;
            const vfloat4 f11 = *(const vfloat4*)&sf[b];
            const vfloat4 f12 = *(const vfloat4*)&sf[b + 16];
            const vfloat4 f21 = *(const vfloat4*)&sf[b + 33 * 16];
            const vfloat4 f22 = *(const vfloat4*)&sf[b + 33 * 16 + 16];
            #pragma unroll
            for (int k = 0; k < 4; ++k) {
                const float pr = f11[k] * wx2 + f12[k] * wx1;
                const float qr = f21[k] * wx2 + f22[k] * wx1;
                m = fmaxf(m, pr * wy2 + qr * wy1);
            }
        }
        // quad max (whole quad shares validity)
        m = fmaxf(m, __shfl_xor(m, 1, 64));
        m = fmaxf(m, __shfl_xor(m, 2, 64));
        if (valid && q == 0) {
            const unsigned fb = __float_as_uint(m);
            const unsigned key = (fb & 0x80000000u) ? ~fb : (fb | 0x80000000u);
            atomicMax(&pooled[n * NBIN + bin], key);
        }
    }
}

// ---------------- Kernel 3: decode pooled keys, broadcast to (N,C,7,7) -----
__global__ __launch_bounds__(256)
void broadcast_out(const unsigned* __restrict__ ws, float* __restrict__ out) {
    __shared__ float pl[NBIN];
    const int n = blockIdx.x, t = threadIdx.x;
    if (t < NBIN) {
        const unsigned key = ws[POOLED_OFF + n * NBIN + t];
        const unsigned fb = (key & 0x80000000u) ? (key ^ 0x80000000u) : ~key;
        pl[t] = __uint_as_float(fb);
    }
    __syncthreads();
    float* o = out + (size_t)n * (CCH * NBIN);
    for (int idx = t; idx < CCH * NBIN; idx += 256)
        __builtin_nontemporal_store(pl[idx % NBIN], o + idx);
}

// ---------------- Fallback (round-1 direct kernel, used if ws too small) ----
__global__ __launch_bounds__(256)
void roialign_direct_kernel(const float* __restrict__ feat,
                            const float* __restrict__ rois,
                            float* __restrict__ out)
{
    const int n = blockIdx.x;
    const int t = threadIdx.x;
    __shared__ float ptmax[196];
    __shared__ float pooled[NBIN];

    const float y0  = rois[n * 4 + 0];
    const float x0  = rois[n * 4 + 1];
    const float sh  = (rois[n * 4 + 2] - y0) / (float)RBIN;
    const float sw  = (rois[n * 4 + 3] - x0) / (float)RBIN;

    const bool active = (t < 196);
    int off11 = 0, off12 = 0, off21 = 0, off22 = 0;
    float wx1 = 0.f, wx2 = 0.f, wy1 = 0.f, wy2 = 0.f;
    if (active) {
        const int py = t / 14, px = t % 14;
        const int by = py >> 1, sy = py & 1;
        const int bx = px >> 1, sx = px & 1;
        const float y = y0 + sh * (float)by + ((sy == 0) ? (sh / 3.0f) : (2.0f * sh / 3.0f));
        const float x = x0 + sw * (float)bx + ((sx == 0) ? (sw / 3.0f) : (2.0f * sw / 3.0f));
        int iy1 = (int)floorf(y), iy2 = iy1 + 1;
        int ix1 = (int)floorf(x), ix2 = ix1 + 1;
        iy1 = min(max(iy1, 0), HH - 1); iy2 = min(max(iy2, 0), HH - 1);
        ix1 = min(max(ix1, 0), WW - 1); ix2 = min(max(ix2, 0), WW - 1);
        wy1 = y - (float)iy1; wy2 = (float)iy2 - y;
        wx1 = x - (float)ix1; wx2 = (float)ix2 - x;
        off11 = iy1 * WW + ix1; off12 = iy1 * WW + ix2;
        off21 = iy2 * WW + ix1; off22 = iy2 * WW + ix2;
    }
    if (active) {
        float m = -INFINITY;
        const float* f = feat;
        #pragma unroll 4
        for (int c = 0; c < CCH; ++c) {
            const float p = f[off11] * wx2 + f[off12] * wx1;
            const float q = f[off21] * wx2 + f[off22] * wx1;
            m = fmaxf(m, p * wy2 + q * wy1);
            f += HWSZ;
        }
        ptmax[t] = m;
    }
    __syncthreads();
    if (t < NBIN) {
        const int by = t / RBIN, bx = t % RBIN;
        const int p00 = (2 * by) * 14 + 2 * bx;
        pooled[t] = fmaxf(fmaxf(ptmax[p00], ptmax[p00 + 1]),
                          fmaxf(ptmax[p00 + 14], ptmax[p00 + 15]));
    }
    __syncthreads();
    float* o = out + (size_t)n * (CCH * NBIN);
    for (int idx = t; idx < CCH * NBIN; idx += 256)
        o[idx] = pooled[idx % NBIN];
}

extern "C" void kernel_launch(void* const* d_in, const int* in_sizes, int n_in,
                              void* d_out, int out_size, void* d_ws, size_t ws_size,
                              hipStream_t stream)
{
    const float* feat = (const float*)d_in[0];   // (256,256,256) fp32
    const float* rois = (const float*)d_in[1];   // (512,4) fp32
    float* out = (float*)d_out;                  // (512,256,7,7) fp32

    if (ws_size < WS_WORDS_NEEDED * 4) {
        roialign_direct_kernel<<<NROI, 256, 0, stream>>>(feat, rois, out);
        return;
    }

    unsigned* ws = (unsigned*)d_ws;

    init_ws<<<(GCOUNT_OFF + NTILE + 255) / 256, 256, 0, stream>>>(ws);
    bin_points<<<NROI / 4, 1024, 0, stream>>>(rois, ws);
    scatter_pool<<<dim3(16, NTILE), 256, 0, stream>>>(feat, rois, ws);
    broadcast_out<<<NROI, 256, 0, stream>>>(ws, out);
}

// Round 10
// 130.805 us; speedup vs baseline: 1.6391x; 1.6391x over previous
//
#include <hip/hip_runtime.h>

#define CCH 256
#define HH  256
#define WW  256
#define HWSZ (HH * WW)
#define NROI 512
#define RBIN 7
#define NBIN (RBIN * RBIN)                    // 49
#define TFEAT_BYTES ((size_t)HWSZ * CCH * 2)  // 32 MiB bf16 HWC

typedef float vfloat4 __attribute__((ext_vector_type(4)));

__device__ __forceinline__ unsigned short f2bf_rne(float f) {
    unsigned u = __float_as_uint(f);
    u = (u + 0x7fffu + ((u >> 16) & 1u)) >> 16;
    return (unsigned short)u;
}

// ---------------- Kernel 1: (C,H,W) fp32 -> (H,W,C) bf16 transpose ----------
// R10: two 64x64 sub-tiles per block; ALL 8 nontemporal loads (128 B/thread)
// issued before any LDS traffic -> 2x outstanding global bytes vs R8.
// grid (HW/128, C/64) = (512, 4). Single-variable test: if T was
// MLP/issue-limited this helps; if HBM-contention-limited (harness poison
// writeback) it's neutral. Fused kernel below is byte-identical to R8.
__global__ __launch_bounds__(256)
void transpose_chw_to_hwc_bf16(const float* __restrict__ feat,
                               unsigned short* __restrict__ tfeat)
{
    __shared__ float tile[64][68];            // 17.4 KB, rows 16B-aligned
    const int t   = threadIdx.x;              // 0..255
    const int hwB = blockIdx.x * 128;
    const int c0  = blockIdx.y * 64;

    const int cl_r = (t >> 4);                // 0..15 (+j*16)
    const int hl_r = (t & 15) * 4;            // 0,4,..,60

    vfloat4 v0[4], v1[4];
    #pragma unroll
    for (int j = 0; j < 4; ++j) {
        v0[j] = __builtin_nontemporal_load(
            (const vfloat4*)(feat + (size_t)(c0 + cl_r + j * 16) * HWSZ + hwB + hl_r));
    }
    #pragma unroll
    for (int j = 0; j < 4; ++j) {
        v1[j] = __builtin_nontemporal_load(
            (const vfloat4*)(feat + (size_t)(c0 + cl_r + j * 16) * HWSZ + hwB + 64 + hl_r));
    }

    const int cl_w = (t & 15) * 4;            // 0,4,..,60

    // ---- sub-tile 0 ----
    #pragma unroll
    for (int j = 0; j < 4; ++j)
        *(vfloat4*)&tile[cl_r + j * 16][hl_r] = v0[j];     // ds_write_b128
    __syncthreads();
    #pragma unroll
    for (int j = 0; j < 4; ++j) {
        const int hl = (t >> 4) + j * 16;     // 0..63
        ushort4 w;
        w.x = f2bf_rne(tile[cl_w][hl]);
        w.y = f2bf_rne(tile[cl_w + 1][hl]);
        w.z = f2bf_rne(tile[cl_w + 2][hl]);
        w.w = f2bf_rne(tile[cl_w + 3][hl]);
        *(ushort4*)(tfeat + (size_t)(hwB + hl) * CCH + c0 + cl_w) = w;
    }
    __syncthreads();

    // ---- sub-tile 1 ----
    #pragma unroll
    for (int j = 0; j < 4; ++j)
        *(vfloat4*)&tile[cl_r + j * 16][hl_r] = v1[j];
    __syncthreads();
    #pragma unroll
    for (int j = 0; j < 4; ++j) {
        const int hl = (t >> 4) + j * 16;
        ushort4 w;
        w.x = f2bf_rne(tile[cl_w][hl]);
        w.y = f2bf_rne(tile[cl_w + 1][hl]);
        w.z = f2bf_rne(tile[cl_w + 2][hl]);
        w.w = f2bf_rne(tile[cl_w + 3][hl]);
        *(ushort4*)(tfeat + (size_t)(hwB + 64 + hl) * CCH + c0 + cl_w) = w;
    }
}

// ---------------- Kernel 2: fused sample + pool + broadcast (R6/R8 exact) ---
// One block per roi: 1024 threads = 16 waves (2 blocks/CU, 32 waves/CU).
// Wave owns a whole bin (2x2 sample points): half-wave (32 lanes x 8ch
// uint4 = 256 ch) owns one point; per-lane register max across points,
// one 6-step butterfly per bin, 16 B/lane loads.
__global__ __launch_bounds__(1024)
void roialign_fused(const unsigned short* __restrict__ tfeat,
                    const float* __restrict__ rois,
                    float* __restrict__ out)
{
    const int n    = blockIdx.x;
    const int t    = threadIdx.x;
    const int wave = t >> 6;                  // 0..15
    const int lane = t & 63;
    const int half = lane >> 5;               // point selector within pair
    const int cOff = (lane & 31) * 8;         // 8 channels per lane

    __shared__ float pooled[NBIN];

    const float y0 = rois[n * 4 + 0];
    const float x0 = rois[n * 4 + 1];
    const float sh = (rois[n * 4 + 2] - y0) / (float)RBIN;
    const float sw = (rois[n * 4 + 3] - x0) / (float)RBIN;

    for (int bin = wave; bin < NBIN; bin += 16) {
        const int by = bin / RBIN;
        const int bx = bin % RBIN;

        float acc[8];
        #pragma unroll
        for (int k = 0; k < 8; ++k) acc[k] = -INFINITY;

        #pragma unroll
        for (int i = 0; i < 2; ++i) {
            const int point = i * 2 + half;   // 0..3 over (i, half)
            const int sy = point >> 1;
            const int sx = point & 1;

            const float y = y0 + sh * (float)by +
                            ((sy == 0) ? (sh / 3.0f) : (2.0f * sh / 3.0f));
            const float x = x0 + sw * (float)bx +
                            ((sx == 0) ? (sw / 3.0f) : (2.0f * sw / 3.0f));

            int iy1 = (int)floorf(y);
            int iy2 = iy1 + 1;
            int ix1 = (int)floorf(x);
            int ix2 = ix1 + 1;
            iy1 = min(max(iy1, 0), HH - 1);
            iy2 = min(max(iy2, 0), HH - 1);
            ix1 = min(max(ix1, 0), WW - 1);
            ix2 = min(max(ix2, 0), WW - 1);

            // weights from clipped indices (matches reference, incl. edge strip)
            const float wy1 = y - (float)iy1;
            const float wy2 = (float)iy2 - y;
            const float wx1 = x - (float)ix1;
            const float wx2 = (float)ix2 - x;

            const uint4 A = *(const uint4*)(tfeat + (size_t)(iy1 * WW + ix1) * CCH + cOff);
            const uint4 B = *(const uint4*)(tfeat + (size_t)(iy1 * WW + ix2) * CCH + cOff);
            const uint4 C = *(const uint4*)(tfeat + (size_t)(iy2 * WW + ix1) * CCH + cOff);
            const uint4 D = *(const uint4*)(tfeat + (size_t)(iy2 * WW + ix2) * CCH + cOff);
            const unsigned* ap = (const unsigned*)&A;
            const unsigned* bp = (const unsigned*)&B;
            const unsigned* cp = (const unsigned*)&C;
            const unsigned* dp = (const unsigned*)&D;

            #pragma unroll
            for (int k = 0; k < 4; ++k) {
                const unsigned ua = ap[k], ub = bp[k], uc = cp[k], ud = dp[k];
                {
                    const float f11 = __uint_as_float(ua << 16);
                    const float f12 = __uint_as_float(ub << 16);
                    const float f21 = __uint_as_float(uc << 16);
                    const float f22 = __uint_as_float(ud << 16);
                    const float p = f11 * wx2 + f12 * wx1;
                    const float q = f21 * wx2 + f22 * wx1;
                    acc[2 * k] = fmaxf(acc[2 * k], p * wy2 + q * wy1);
                }
                {
                    const float f11 = __uint_as_float(ua & 0xffff0000u);
                    const float f12 = __uint_as_float(ub & 0xffff0000u);
                    const float f21 = __uint_as_float(uc & 0xffff0000u);
                    const float f22 = __uint_as_float(ud & 0xffff0000u);
                    const float p = f11 * wx2 + f12 * wx1;
                    const float q = f21 * wx2 + f22 * wx1;
                    acc[2 * k + 1] = fmaxf(acc[2 * k + 1], p * wy2 + q * wy1);
                }
            }
        }

        float m = fmaxf(fmaxf(fmaxf(acc[0], acc[1]), fmaxf(acc[2], acc[3])),
                        fmaxf(fmaxf(acc[4], acc[5]), fmaxf(acc[6], acc[7])));

        #pragma unroll
        for (int off = 32; off > 0; off >>= 1)
            m = fmaxf(m, __shfl_xor(m, off, 64));

        if (lane == 0) pooled[bin] = m;
    }
    __syncthreads();

    float* o = out + (size_t)n * (CCH * NBIN);
    #pragma unroll
    for (int k = 0; k < 13; ++k) {            // 13*1024 >= 12544
        const int idx = t + k * 1024;
        if (idx < CCH * NBIN)
            __builtin_nontemporal_store(pooled[idx % NBIN], o + idx);
    }
}

// ---------------- Fallback (round-1 direct kernel, used if ws too small) ----
__global__ __launch_bounds__(256)
void roialign_direct_kernel(const float* __restrict__ feat,
                            const float* __restrict__ rois,
                            float* __restrict__ out)
{
    const int n = blockIdx.x;
    const int t = threadIdx.x;
    __shared__ float ptmax[196];
    __shared__ float pooled[NBIN];

    const float y0  = rois[n * 4 + 0];
    const float x0  = rois[n * 4 + 1];
    const float sh  = (rois[n * 4 + 2] - y0) / (float)RBIN;
    const float sw  = (rois[n * 4 + 3] - x0) / (float)RBIN;

    const bool active = (t < 196);
    int off11 = 0, off12 = 0, off21 = 0, off22 = 0;
    float wx1 = 0.f, wx2 = 0.f, wy1 = 0.f, wy2 = 0.f;
    if (active) {
        const int py = t / 14, px = t % 14;
        const int by = py >> 1, sy = py & 1;
        const int bx = px >> 1, sx = px & 1;
        const float y = y0 + sh * (float)by + ((sy == 0) ? (sh / 3.0f) : (2.0f * sh / 3.0f));
        const float x = x0 + sw * (float)bx + ((sx == 0) ? (sw / 3.0f) : (2.0f * sw / 3.0f));
        int iy1 = (int)floorf(y), iy2 = iy1 + 1;
        int ix1 = (int)floorf(x), ix2 = ix1 + 1;
        iy1 = min(max(iy1, 0), HH - 1); iy2 = min(max(iy2, 0), HH - 1);
        ix1 = min(max(ix1, 0), WW - 1); ix2 = min(max(ix2, 0), WW - 1);
        wy1 = y - (float)iy1; wy2 = (float)iy2 - y;
        wx1 = x - (float)ix1; wx2 = (float)ix2 - x;
        off11 = iy1 * WW + ix1; off12 = iy1 * WW + ix2;
        off21 = iy2 * WW + ix1; off22 = iy2 * WW + ix2;
    }
    if (active) {
        float m = -INFINITY;
        const float* f = feat;
        #pragma unroll 4
        for (int c = 0; c < CCH; ++c) {
            const float p = f[off11] * wx2 + f[off12] * wx1;
            const float q = f[off21] * wx2 + f[off22] * wx1;
            m = fmaxf(m, p * wy2 + q * wy1);
            f += HWSZ;
        }
        ptmax[t] = m;
    }
    __syncthreads();
    if (t < NBIN) {
        const int by = t / RBIN, bx = t % RBIN;
        const int p00 = (2 * by) * 14 + 2 * bx;
        pooled[t] = fmaxf(fmaxf(ptmax[p00], ptmax[p00 + 1]),
                          fmaxf(ptmax[p00 + 14], ptmax[p00 + 15]));
    }
    __syncthreads();
    float* o = out + (size_t)n * (CCH * NBIN);
    for (int idx = t; idx < CCH * NBIN; idx += 256)
        o[idx] = pooled[idx % NBIN];
}

extern "C" void kernel_launch(void* const* d_in, const int* in_sizes, int n_in,
                              void* d_out, int out_size, void* d_ws, size_t ws_size,
                              hipStream_t stream)
{
    const float* feat = (const float*)d_in[0];   // (256,256,256) fp32
    const float* rois = (const float*)d_in[1];   // (512,4) fp32
    float* out = (float*)d_out;                  // (512,256,7,7) fp32

    if (ws_size < TFEAT_BYTES) {
        roialign_direct_kernel<<<NROI, 256, 0, stream>>>(feat, rois, out);
        return;
    }

    unsigned short* tfeat = (unsigned short*)d_ws;

    dim3 tgrid(HWSZ / 128, CCH / 64);
    transpose_chw_to_hwc_bf16<<<tgrid, 256, 0, stream>>>(feat, tfeat);

    roialign_fused<<<NROI, 1024, 0, stream>>>(tfeat, rois, out);
}

// Round 11
// 129.667 us; speedup vs baseline: 1.6535x; 1.0088x over previous
//
#include <hip/hip_runtime.h>

#define CCH 256
#define HH  256
#define WW  256
#define HWSZ (HH * WW)
#define NROI 512
#define RBIN 7
#define NBIN (RBIN * RBIN)                    // 49
#define TFEAT_BYTES ((size_t)HWSZ * CCH * 2)  // 32 MiB bf16 HWC

typedef float vfloat4 __attribute__((ext_vector_type(4)));

__device__ __forceinline__ unsigned short f2bf_rne(float f) {
    unsigned u = __float_as_uint(f);
    u = (u + 0x7fffu + ((u >> 16) & 1u)) >> 16;
    return (unsigned short)u;
}

// ---------------- Kernel 1: (C,H,W) fp32 -> (H,W,C) bf16 transpose ----------
// R11: XOR-swizzled LDS, conflict-free in BOTH passes.
//   tile addr(cl, hl) = cl*64 + (hl ^ 4*((cl>>2)&7)); row stride 64 floats
//   (== 0 mod 32 banks), swizzle spreads columns.
//   * write pass: p = 4*fc ^ 4*((cl>>2)&7); per wave cl>>2 const -> 16-way
//     permutation of float4 slots -> conflict-free ds_write_b128, 16B-aligned.
//   * read pass: rows cl_w..cl_w+3 share (cl>>2)&7 = (t&15)&7 -> bank =
//     ((t>>4)+16j) ^ 4*((t&15)&7): bits0-1 x bits2-4 = all 32 banks,
//     2 lanes/bank = free (m136). R8's 68-stride had 8 banks/64 lanes.
// grid (HW/64, C/64) = (1024, 4), 16 KB LDS/block.
__global__ __launch_bounds__(256)
void transpose_chw_to_hwc_bf16(const float* __restrict__ feat,
                               unsigned short* __restrict__ tfeat)
{
    __shared__ __align__(16) float tile[64 * 64];  // 16 KB, swizzled
    const int t   = threadIdx.x;              // 0..255
    const int hw0 = blockIdx.x * 64;
    const int c0  = blockIdx.y * 64;

    const int cl_r = t >> 4;                  // 0..15 (+j*16)
    const int fc   = t & 15;                  // float4 column 0..15

    vfloat4 v[4];
    #pragma unroll
    for (int j = 0; j < 4; ++j) {
        v[j] = __builtin_nontemporal_load(
            (const vfloat4*)(feat + (size_t)(c0 + cl_r + j * 16) * HWSZ + hw0 + 4 * fc));
    }
    #pragma unroll
    for (int j = 0; j < 4; ++j) {
        const int cl = cl_r + j * 16;
        const int p  = (4 * fc) ^ (4 * ((cl >> 2) & 7));
        *(vfloat4*)&tile[cl * 64 + p] = v[j];          // ds_write_b128
    }
    __syncthreads();

    const int cl_w = (t & 15) * 4;            // 0,4,..,60
    const int swz  = 4 * ((t & 15) & 7);      // == 4*(((cl_w+i)>>2)&7) for i<4
    #pragma unroll
    for (int j = 0; j < 4; ++j) {
        const int hl = (t >> 4) + j * 16;     // 0..63 over passes
        const int pc = hl ^ swz;
        ushort4 w;
        w.x = f2bf_rne(tile[(cl_w + 0) * 64 + pc]);
        w.y = f2bf_rne(tile[(cl_w + 1) * 64 + pc]);
        w.z = f2bf_rne(tile[(cl_w + 2) * 64 + pc]);
        w.w = f2bf_rne(tile[(cl_w + 3) * 64 + pc]);
        // 16 lanes (same hl) cover 64 consecutive channels -> 128 B segment
        *(ushort4*)(tfeat + (size_t)(hw0 + hl) * CCH + c0 + cl_w) = w;
    }
}

// ---------------- Kernel 2: fused sample + pool + broadcast (R6/R8 exact) ---
// One block per roi: 1024 threads = 16 waves (2 blocks/CU, 32 waves/CU).
// Wave owns a whole bin (2x2 sample points): half-wave (32 lanes x 8ch
// uint4 = 256 ch) owns one point; per-lane register max across points,
// one 6-step butterfly per bin, 16 B/lane loads.
__global__ __launch_bounds__(1024)
void roialign_fused(const unsigned short* __restrict__ tfeat,
                    const float* __restrict__ rois,
                    float* __restrict__ out)
{
    const int n    = blockIdx.x;
    const int t    = threadIdx.x;
    const int wave = t >> 6;                  // 0..15
    const int lane = t & 63;
    const int half = lane >> 5;               // point selector within pair
    const int cOff = (lane & 31) * 8;         // 8 channels per lane

    __shared__ float pooled[NBIN];

    const float y0 = rois[n * 4 + 0];
    const float x0 = rois[n * 4 + 1];
    const float sh = (rois[n * 4 + 2] - y0) / (float)RBIN;
    const float sw = (rois[n * 4 + 3] - x0) / (float)RBIN;

    for (int bin = wave; bin < NBIN; bin += 16) {
        const int by = bin / RBIN;
        const int bx = bin % RBIN;

        float acc[8];
        #pragma unroll
        for (int k = 0; k < 8; ++k) acc[k] = -INFINITY;

        #pragma unroll
        for (int i = 0; i < 2; ++i) {
            const int point = i * 2 + half;   // 0..3 over (i, half)
            const int sy = point >> 1;
            const int sx = point & 1;

            const float y = y0 + sh * (float)by +
                            ((sy == 0) ? (sh / 3.0f) : (2.0f * sh / 3.0f));
            const float x = x0 + sw * (float)bx +
                            ((sx == 0) ? (sw / 3.0f) : (2.0f * sw / 3.0f));

            int iy1 = (int)floorf(y);
            int iy2 = iy1 + 1;
            int ix1 = (int)floorf(x);
            int ix2 = ix1 + 1;
            iy1 = min(max(iy1, 0), HH - 1);
            iy2 = min(max(iy2, 0), HH - 1);
            ix1 = min(max(ix1, 0), WW - 1);
            ix2 = min(max(ix2, 0), WW - 1);

            // weights from clipped indices (matches reference, incl. edge strip)
            const float wy1 = y - (float)iy1;
            const float wy2 = (float)iy2 - y;
            const float wx1 = x - (float)ix1;
            const float wx2 = (float)ix2 - x;

            const uint4 A = *(const uint4*)(tfeat + (size_t)(iy1 * WW + ix1) * CCH + cOff);
            const uint4 B = *(const uint4*)(tfeat + (size_t)(iy1 * WW + ix2) * CCH + cOff);
            const uint4 C = *(const uint4*)(tfeat + (size_t)(iy2 * WW + ix1) * CCH + cOff);
            const uint4 D = *(const uint4*)(tfeat + (size_t)(iy2 * WW + ix2) * CCH + cOff);
            const unsigned* ap = (const unsigned*)&A;
            const unsigned* bp = (const unsigned*)&B;
            const unsigned* cp = (const unsigned*)&C;
            const unsigned* dp = (const unsigned*)&D;

            #pragma unroll
            for (int k = 0; k < 4; ++k) {
                const unsigned ua = ap[k], ub = bp[k], uc = cp[k], ud = dp[k];
                {
                    const float f11 = __uint_as_float(ua << 16);
                    const float f12 = __uint_as_float(ub << 16);
                    const float f21 = __uint_as_float(uc << 16);
                    const float f22 = __uint_as_float(ud << 16);
                    const float p = f11 * wx2 + f12 * wx1;
                    const float q = f21 * wx2 + f22 * wx1;
                    acc[2 * k] = fmaxf(acc[2 * k], p * wy2 + q * wy1);
                }
                {
                    const float f11 = __uint_as_float(ua & 0xffff0000u);
                    const float f12 = __uint_as_float(ub & 0xffff0000u);
                    const float f21 = __uint_as_float(uc & 0xffff0000u);
                    const float f22 = __uint_as_float(ud & 0xffff0000u);
                    const float p = f11 * wx2 + f12 * wx1;
                    const float q = f21 * wx2 + f22 * wx1;
                    acc[2 * k + 1] = fmaxf(acc[2 * k + 1], p * wy2 + q * wy1);
                }
            }
        }

        float m = fmaxf(fmaxf(fmaxf(acc[0], acc[1]), fmaxf(acc[2], acc[3])),
                        fmaxf(fmaxf(acc[4], acc[5]), fmaxf(acc[6], acc[7])));

        #pragma unroll
        for (int off = 32; off > 0; off >>= 1)
            m = fmaxf(m, __shfl_xor(m, off, 64));

        if (lane == 0) pooled[bin] = m;
    }
    __syncthreads();

    float* o = out + (size_t)n * (CCH * NBIN);
    #pragma unroll
    for (int k = 0; k < 13; ++k) {            // 13*1024 >= 12544
        const int idx = t + k * 1024;
        if (idx < CCH * NBIN)
            __builtin_nontemporal_store(pooled[idx % NBIN], o + idx);
    }
}

// ---------------- Fallback (round-1 direct kernel, used if ws too small) ----
__global__ __launch_bounds__(256)
void roialign_direct_kernel(const float* __restrict__ feat,
                            const float* __restrict__ rois,
                            float* __restrict__ out)
{
    const int n = blockIdx.x;
    const int t = threadIdx.x;
    __shared__ float ptmax[196];
    __shared__ float pooled[NBIN];

    const float y0  = rois[n * 4 + 0];
    const float x0  = rois[n * 4 + 1];
    const float sh  = (rois[n * 4 + 2] - y0) / (float)RBIN;
    const float sw  = (rois[n * 4 + 3] - x0) / (float)RBIN;

    const bool active = (t < 196);
    int off11 = 0, off12 = 0, off21 = 0, off22 = 0;
    float wx1 = 0.f, wx2 = 0.f, wy1 = 0.f, wy2 = 0.f;
    if (active) {
        const int py = t / 14, px = t % 14;
        const int by = py >> 1, sy = py & 1;
        const int bx = px >> 1, sx = px & 1;
        const float y = y0 + sh * (float)by + ((sy == 0) ? (sh / 3.0f) : (2.0f * sh / 3.0f));
        const float x = x0 + sw * (float)bx + ((sx == 0) ? (sw / 3.0f) : (2.0f * sw / 3.0f));
        int iy1 = (int)floorf(y), iy2 = iy1 + 1;
        int ix1 = (int)floorf(x), ix2 = ix1 + 1;
        iy1 = min(max(iy1, 0), HH - 1); iy2 = min(max(iy2, 0), HH - 1);
        ix1 = min(max(ix1, 0), WW - 1); ix2 = min(max(ix2, 0), WW - 1);
        wy1 = y - (float)iy1; wy2 = (float)iy2 - y;
        wx1 = x - (float)ix1; wx2 = (float)ix2 - x;
        off11 = iy1 * WW + ix1; off12 = iy1 * WW + ix2;
        off21 = iy2 * WW + ix1; off22 = iy2 * WW + ix2;
    }
    if (active) {
        float m = -INFINITY;
        const float* f = feat;
        #pragma unroll 4
        for (int c = 0; c < CCH; ++c) {
            const float p = f[off11] * wx2 + f[off12] * wx1;
            const float q = f[off21] * wx2 + f[off22] * wx1;
            m = fmaxf(m, p * wy2 + q * wy1);
            f += HWSZ;
        }
        ptmax[t] = m;
    }
    __syncthreads();
    if (t < NBIN) {
        const int by = t / RBIN, bx = t % RBIN;
        const int p00 = (2 * by) * 14 + 2 * bx;
        pooled[t] = fmaxf(fmaxf(ptmax[p00], ptmax[p00 + 1]),
                          fmaxf(ptmax[p00 + 14], ptmax[p00 + 15]));
    }
    __syncthreads();
    float* o = out + (size_t)n * (CCH * NBIN);
    for (int idx = t; idx < CCH * NBIN; idx += 256)
        o[idx] = pooled[idx % NBIN];
}

extern "C" void kernel_launch(void* const* d_in, const int* in_sizes, int n_in,
                              void* d_out, int out_size, void* d_ws, size_t ws_size,
                              hipStream_t stream)
{
    const float* feat = (const float*)d_in[0];   // (256,256,256) fp32
    const float* rois = (const float*)d_in[1];   // (512,4) fp32
    float* out = (float*)d_out;                  // (512,256,7,7) fp32

    if (ws_size < TFEAT_BYTES) {
        roialign_direct_kernel<<<NROI, 256, 0, stream>>>(feat, rois, out);
        return;
    }

    unsigned short* tfeat = (unsigned short*)d_ws;

    dim3 tgrid(HWSZ / 64, CCH / 64);
    transpose_chw_to_hwc_bf16<<<tgrid, 256, 0, stream>>>(feat, tfeat);

    roialign_fused<<<NROI, 1024, 0, stream>>>(tfeat, rois, out);
}